// Round 8
// baseline (824.724 us; speedup 1.0000x reference)
//
#include <hip/hip_runtime.h>
#include <math.h>

// ---- problem constants ----
#define B_      2
#define EMB_    384
#define NH_     8
#define HD_     48
#define NTOK    1729       // NPATCH + 1
#define NPATCH_ 1728
#define MLP_    1536
#define NL_     6
#define NC_     2
#define BSTR    1792       // per-batch row stride (padded tokens)
#define M_PAD   3584       // 2 * BSTR
#define SCALE_  0.14433756729740643f   // 1/sqrt(48)
#define OPSZ    ((size_t)B_ * BSTR * EMB_)

typedef __bf16 bf16x8 __attribute__((ext_vector_type(8)));
typedef float floatx4 __attribute__((ext_vector_type(4)));
typedef _Float16 halfx4 __attribute__((ext_vector_type(4)));
typedef unsigned short u16;

__device__ __forceinline__ u16 f2b(float f) {
    unsigned int u = __float_as_uint(f);
    return (u16)((u + 0x7FFFu + ((u >> 16) & 1u)) >> 16);
}
__device__ __forceinline__ u16 f2h(float f) {
    _Float16 h = (_Float16)f;
    return __builtin_bit_cast(unsigned short, h);
}
__device__ __forceinline__ bf16x8 ld8(const u16* p) {       // 16B-aligned
    return *(const bf16x8*)p;
}

// ============================================================
// Merged fp32 -> bf16 convert: conv_w | x | qkv_w | proj_w | mlp_w1 | mlp_w2
// ============================================================
#define CW_N  196608      // 384*512
#define P0_   196608
#define P1_   1966080     // + x (1769472)
#define P2_   4620288     // + qkv_w (2654208)
#define P3_   5505024     // + proj_w (884736)
#define P4_   9043968     // + mlp_w1 (3538944)
#define P5_   12582912    // + mlp_w2 (3538944)
__global__ __launch_bounds__(256) void cvt_all(
    const float* __restrict__ cw, const float* __restrict__ x,
    const float* __restrict__ qw, const float* __restrict__ pw,
    const float* __restrict__ w1, const float* __restrict__ w2,
    u16* __restrict__ cwb, u16* __restrict__ xb, u16* __restrict__ qwb,
    u16* __restrict__ pwb, u16* __restrict__ w1b, u16* __restrict__ w2b)
{
    int i = (blockIdx.x * 256 + threadIdx.x) * 4;
    const float* s; u16* d; int off;
    if      (i < P0_) { s = cw; d = cwb; off = 0; }
    else if (i < P1_) { s = x;  d = xb;  off = P0_; }
    else if (i < P2_) { s = qw; d = qwb; off = P1_; }
    else if (i < P3_) { s = pw; d = pwb; off = P2_; }
    else if (i < P4_) { s = w1; d = w1b; off = P3_; }
    else              { s = w2; d = w2b; off = P4_; }
    i -= off;
    float4 v = *(const float4*)(s + i);
    ushort4 o;
    o.x = f2b(v.x); o.y = f2b(v.y); o.z = f2b(v.z); o.w = f2b(v.w);
    *(ushort4*)(d + i) = o;
}

// ============================================================
// Patch embed as bf16 MFMA GEMM + per-row LN stats emission.
// grid (6, 54), block 256. Stats: sumb/sqb[row][12] = partial
// Sigma x, Sigma x^2 per (N-block nb, wave col-half w&1).
// ============================================================
__global__ __launch_bounds__(256) void patch_mfma(
    const u16* __restrict__ xb, const u16* __restrict__ cwb,
    const float* __restrict__ cb, const float* __restrict__ cls,
    const float* __restrict__ pos, float* __restrict__ t,
    float* __restrict__ sumb, float* __restrict__ sqb)
{
    __shared__ __align__(16) u16 As[64][40];
    __shared__ __align__(16) u16 Bs[64][40];
    const int tid  = threadIdx.x;
    const int lane = tid & 63, w = tid >> 6;
    const int wm = (w >> 1) * 32, wn = (w & 1) * 32;
    const int m0g = blockIdx.y * 64, n0g = blockIdx.x * 64;
    const int cl = lane & 15, kh = (lane >> 4) * 8;   // cl = C/D col lane
    const int nb = blockIdx.x;

    // cls rows + their stats (full sum in slot 0, zeros elsewhere)
    if (blockIdx.x == 0 && blockIdx.y == 0 && w < 2) {
        int bb = w;
        float pv = 0.f, pq = 0.f;
#pragma unroll
        for (int j = 0; j < 6; ++j) {
            int e = lane + 64 * j;
            float v = cls[e] + pos[e];
            t[(size_t)bb * BSTR * EMB_ + e] = v;
            pv += v; pq += v * v;
        }
#pragma unroll
        for (int off = 1; off < 64; off <<= 1) {
            pv += __shfl_xor(pv, off, 64);
            pq += __shfl_xor(pq, off, 64);
        }
        if (lane < 12) {
            sumb[(size_t)bb * BSTR * 12 + lane] = (lane == 0) ? pv : 0.f;
            sqb [(size_t)bb * BSTR * 12 + lane] = (lane == 0) ? pq : 0.f;
        }
    }

    const int sm = tid >> 2, skc = tid & 3;
    const int gm_s = m0g + sm;
    const int bb_s = gm_s / 1728, p_s = gm_s % 1728;
    const int pz = p_s / 144, py = (p_s / 12) % 12, px = p_s % 12;

    floatx4 acc[2][2];
#pragma unroll
    for (int i = 0; i < 2; ++i)
#pragma unroll
        for (int j = 0; j < 2; ++j) acc[i][j] = (floatx4){0.f, 0.f, 0.f, 0.f};

    for (int k0 = 0; k0 < 512; k0 += 32) {
        {
            int k = k0 + skc * 8;
            int dz = k >> 6, dy = (k >> 3) & 7;
            *(uint4*)&As[sm][skc * 8] =
                *(const uint4*)(xb + ((size_t)(bb_s * 96 + pz * 8 + dz) * 96 +
                                      py * 8 + dy) * 96 + px * 8);
            *(uint4*)&Bs[sm][skc * 8] =
                *(const uint4*)(cwb + (size_t)(n0g + sm) * 512 + k);
        }
        __syncthreads();
        bf16x8 af[2], bfr[2];
#pragma unroll
        for (int i = 0; i < 2; ++i) af[i] = ld8(&As[wm + 16 * i + cl][kh]);
#pragma unroll
        for (int j = 0; j < 2; ++j) bfr[j] = ld8(&Bs[wn + 16 * j + cl][kh]);
#pragma unroll
        for (int i = 0; i < 2; ++i)
#pragma unroll
            for (int j = 0; j < 2; ++j)
                acc[i][j] = __builtin_amdgcn_mfma_f32_16x16x32_bf16(
                    af[i], bfr[j], acc[i][j], 0, 0, 0);
        __syncthreads();
    }

    const int r0 = (lane >> 4) * 4;
    float vv[2][2][4];
#pragma unroll
    for (int j = 0; j < 2; ++j) {
        int gn = n0g + wn + 16 * j + cl;
        float bn = cb[gn];
#pragma unroll
        for (int i = 0; i < 2; ++i) {
#pragma unroll
            for (int r = 0; r < 4; ++r) {
                int gm = m0g + wm + 16 * i + r0 + r;
                int bb = gm / 1728, pp = gm % 1728;
                float v = acc[i][j][r] + bn + pos[(size_t)(1 + pp) * EMB_ + gn];
                t[((size_t)bb * BSTR + 1 + pp) * EMB_ + gn] = v;
                vv[i][j][r] = v;
            }
        }
    }
#pragma unroll
    for (int i = 0; i < 2; ++i)
#pragma unroll
        for (int r = 0; r < 4; ++r) {
            float pv = vv[i][0][r] + vv[i][1][r];
            float pq = vv[i][0][r] * vv[i][0][r] + vv[i][1][r] * vv[i][1][r];
#pragma unroll
            for (int off = 1; off < 16; off <<= 1) {
                pv += __shfl_xor(pv, off, 64);
                pq += __shfl_xor(pq, off, 64);
            }
            if (cl == 0) {
                int gm = m0g + wm + 16 * i + r0 + r;
                int bb = gm / 1728, pp = gm % 1728;
                size_t rowt = (size_t)bb * BSTR + 1 + pp;
                sumb[rowt * 12 + nb * 2 + (w & 1)] = pv;
                sqb [rowt * 12 + nb * 2 + (w & 1)] = pq;
            }
        }
}

// ============================================================
// GEMM with LN fused into A-staging: C = act(LN(t) @ W^T + bias)
// A rows' mean/rstd from producer-emitted sumb/sqb (12 slots/row).
// K = EMB_ = 384. VT: qkv V-columns -> vT transposed f16.
// ============================================================
template<int FI, int FJ, int ACT, int VT>
__global__ __launch_bounds__(256) void gemm_ln(
    const float* __restrict__ T, const float* __restrict__ sumb,
    const float* __restrict__ sqb, const float* __restrict__ lnw,
    const float* __restrict__ lnb, const u16* __restrict__ W,
    const float* __restrict__ bias, u16* __restrict__ Cb,
    u16* __restrict__ vt, int N)
{
    constexpr int TM = 32 * FI;
    constexpr int TN = 32 * FJ;
    __shared__ __align__(16) u16 As[TM][40];
    __shared__ __align__(16) u16 Bs[TN][40];
    __shared__ float meanr[TM], rstdr[TM];
    const int tid  = threadIdx.x;
    const int lane = tid & 63, w = tid >> 6;
    const int wm = (w >> 1) * (16 * FI);
    const int wn = (w & 1) * (16 * FJ);
    const int m0g = blockIdx.y * TM, n0g = blockIdx.x * TN;
    const int cl = lane & 15, kh = (lane >> 4) * 8;

    if (tid < TM) {
        size_t row = m0g + tid;
        float s = 0.f, q = 0.f;
#pragma unroll
        for (int i = 0; i < 12; ++i) {
            s += sumb[row * 12 + i];
            q += sqb [row * 12 + i];
        }
        float mu = s * (1.0f / EMB_);
        float va = fmaxf(q * (1.0f / EMB_) - mu * mu, 0.f);  // clamp: pad rows
        meanr[tid] = mu;
        rstdr[tid] = rsqrtf(va + 1e-5f);
    }
    __syncthreads();

    floatx4 acc[FI][FJ];
#pragma unroll
    for (int i = 0; i < FI; ++i)
#pragma unroll
        for (int j = 0; j < FJ; ++j)
            acc[i][j] = (floatx4){0.f, 0.f, 0.f, 0.f};

    for (int k0 = 0; k0 < EMB_; k0 += 32) {
        for (int c = tid; c < TM * 4; c += 256) {
            int m = c >> 2, kc = c & 3;
            int k = k0 + kc * 8;
            const float* tr = T + (size_t)(m0g + m) * EMB_ + k;
            float4 a0 = *(const float4*)tr;
            float4 a1 = *(const float4*)(tr + 4);
            float4 w0 = *(const float4*)(lnw + k);
            float4 w1 = *(const float4*)(lnw + k + 4);
            float4 b0 = *(const float4*)(lnb + k);
            float4 b1 = *(const float4*)(lnb + k + 4);
            float mu = meanr[m], rs = rstdr[m];
            ushort4 lo, hi;
            lo.x = f2b((a0.x - mu) * rs * w0.x + b0.x);
            lo.y = f2b((a0.y - mu) * rs * w0.y + b0.y);
            lo.z = f2b((a0.z - mu) * rs * w0.z + b0.z);
            lo.w = f2b((a0.w - mu) * rs * w0.w + b0.w);
            hi.x = f2b((a1.x - mu) * rs * w1.x + b1.x);
            hi.y = f2b((a1.y - mu) * rs * w1.y + b1.y);
            hi.z = f2b((a1.z - mu) * rs * w1.z + b1.z);
            hi.w = f2b((a1.w - mu) * rs * w1.w + b1.w);
            *(ushort4*)&As[m][kc * 8]     = lo;
            *(ushort4*)&As[m][kc * 8 + 4] = hi;
        }
        for (int c = tid; c < TN * 4; c += 256) {
            int n = c >> 2, kc = c & 3;
            *(uint4*)&Bs[n][kc * 8] =
                *(const uint4*)(W + (size_t)(n0g + n) * EMB_ + k0 + kc * 8);
        }
        __syncthreads();

        bf16x8 af[FI], bfr[FJ];
#pragma unroll
        for (int i = 0; i < FI; ++i)
            af[i] = ld8(&As[wm + 16 * i + cl][kh]);
#pragma unroll
        for (int j = 0; j < FJ; ++j)
            bfr[j] = ld8(&Bs[wn + 16 * j + cl][kh]);
#pragma unroll
        for (int i = 0; i < FI; ++i)
#pragma unroll
            for (int j = 0; j < FJ; ++j)
                acc[i][j] = __builtin_amdgcn_mfma_f32_16x16x32_bf16(
                    af[i], bfr[j], acc[i][j], 0, 0, 0);
        __syncthreads();
    }

    const int r0 = (lane >> 4) * 4;
#pragma unroll
    for (int j = 0; j < FJ; ++j) {
        int gn = n0g + wn + 16 * j + cl;
        float bn = bias[gn];
#pragma unroll
        for (int i = 0; i < FI; ++i) {
            int gm0 = m0g + wm + 16 * i + r0;
            float v[4];
#pragma unroll
            for (int r = 0; r < 4; ++r) {
                float vvv = acc[i][j][r] + bn;
                if (ACT) vvv = 0.5f * vvv * (1.0f + erff(vvv * 0.70710678118654752f));
                v[r] = vvv;
            }
            if (VT && gn >= 768) {
                int hh = (gn - 768) / 48, dd = (gn - 768) % 48;
                int bb = gm0 / BSTR, tok = gm0 - bb * BSTR;
                ushort4 o;
                o.x = f2h(v[0]); o.y = f2h(v[1]); o.z = f2h(v[2]); o.w = f2h(v[3]);
                *(ushort4*)(vt + ((size_t)(bb * 8 + hh) * 48 + dd) * BSTR + tok) = o;
            } else {
#pragma unroll
                for (int r = 0; r < 4; ++r)
                    Cb[(size_t)(gm0 + r) * N + gn] = f2b(v[r]);
            }
        }
    }
}

// ============================================================
// GEMM (FI=1,FJ=2) with residual + LN-stats emission:
//   t += A @ W^T + bias;  emit per-row Sigma/Sigma^2 partials.
// COMBINE: A = bf16((op0+op1)/(l0+l1)) on the fly (attn splits).
// N = 384 (6 N-blocks -> stats slots nb*2 + (w&1)).
// ============================================================
template<int COMBINE>
__global__ __launch_bounds__(256) void gemm_res(
    const u16* __restrict__ A, const u16* __restrict__ op,
    const float* __restrict__ lp, const u16* __restrict__ W,
    const float* __restrict__ bias, float* __restrict__ T,
    float* __restrict__ sumb, float* __restrict__ sqb, int K)
{
    constexpr int TM = 32, TN = 64;
    __shared__ __align__(16) u16 As[TM][40];
    __shared__ __align__(16) u16 Bs[TN][40];
    const int tid  = threadIdx.x;
    const int lane = tid & 63, w = tid >> 6;
    const int wm = (w >> 1) * 16;
    const int wn = (w & 1) * 32;
    const int m0g = blockIdx.y * TM, n0g = blockIdx.x * TN;
    const int cl = lane & 15, kh = (lane >> 4) * 8;
    const int nb = blockIdx.x;

    floatx4 acc[2];
    acc[0] = (floatx4){0.f, 0.f, 0.f, 0.f};
    acc[1] = (floatx4){0.f, 0.f, 0.f, 0.f};

    for (int k0 = 0; k0 < K; k0 += 32) {
        if (tid < TM * 4) {
            int m = tid >> 2, kc = tid & 3;
            int kg = k0 + kc * 8;
            int row = m0g + m;
            if (COMBINE) {
                int hh = kg / 48;
                const u16* o0 = op + (size_t)row * EMB_ + kg;
                ushort4 x0 = *(const ushort4*)o0;
                ushort4 x1 = *(const ushort4*)(o0 + 4);
                ushort4 y0 = *(const ushort4*)(o0 + OPSZ);
                ushort4 y1 = *(const ushort4*)(o0 + OPSZ + 4);
                halfx4 ha0 = __builtin_bit_cast(halfx4, x0);
                halfx4 ha1 = __builtin_bit_cast(halfx4, x1);
                halfx4 hb0 = __builtin_bit_cast(halfx4, y0);
                halfx4 hb1 = __builtin_bit_cast(halfx4, y1);
                float l0 = lp[(size_t)row * NH_ + hh];
                float l1 = lp[((size_t)B_ * BSTR + row) * NH_ + hh];
                float rinv = 1.0f / (l0 + l1);
                ushort4 lo, hi;
                lo.x = f2b(((float)ha0[0] + (float)hb0[0]) * rinv);
                lo.y = f2b(((float)ha0[1] + (float)hb0[1]) * rinv);
                lo.z = f2b(((float)ha0[2] + (float)hb0[2]) * rinv);
                lo.w = f2b(((float)ha0[3] + (float)hb0[3]) * rinv);
                hi.x = f2b(((float)ha1[0] + (float)hb1[0]) * rinv);
                hi.y = f2b(((float)ha1[1] + (float)hb1[1]) * rinv);
                hi.z = f2b(((float)ha1[2] + (float)hb1[2]) * rinv);
                hi.w = f2b(((float)ha1[3] + (float)hb1[3]) * rinv);
                *(ushort4*)&As[m][kc * 8]     = lo;
                *(ushort4*)&As[m][kc * 8 + 4] = hi;
            } else {
                *(uint4*)&As[m][kc * 8] =
                    *(const uint4*)(A + (size_t)row * K + kg);
            }
        }
        {
            int n = tid >> 2, kc = tid & 3;
            *(uint4*)&Bs[n][kc * 8] =
                *(const uint4*)(W + (size_t)(n0g + n) * K + k0 + kc * 8);
        }
        __syncthreads();

        bf16x8 af = ld8(&As[wm + cl][kh]);
        bf16x8 b0 = ld8(&Bs[wn + cl][kh]);
        bf16x8 b1 = ld8(&Bs[wn + 16 + cl][kh]);
        acc[0] = __builtin_amdgcn_mfma_f32_16x16x32_bf16(af, b0, acc[0], 0, 0, 0);
        acc[1] = __builtin_amdgcn_mfma_f32_16x16x32_bf16(af, b1, acc[1], 0, 0, 0);
        __syncthreads();
    }

    const int r0 = (lane >> 4) * 4;
    const int gm0 = m0g + wm + r0;
    float vv[2][4];
#pragma unroll
    for (int j = 0; j < 2; ++j) {
        int gn = n0g + wn + 16 * j + cl;
        float bn = bias[gn];
#pragma unroll
        for (int r = 0; r < 4; ++r) {
            float v = acc[j][r] + bn + T[(size_t)(gm0 + r) * EMB_ + gn];
            T[(size_t)(gm0 + r) * EMB_ + gn] = v;
            vv[j][r] = v;
        }
    }
#pragma unroll
    for (int r = 0; r < 4; ++r) {
        float pv = vv[0][r] + vv[1][r];
        float pq = vv[0][r] * vv[0][r] + vv[1][r] * vv[1][r];
#pragma unroll
        for (int off = 1; off < 16; off <<= 1) {
            pv += __shfl_xor(pv, off, 64);
            pq += __shfl_xor(pq, off, 64);
        }
        if (cl == 0) {
            sumb[(size_t)(gm0 + r) * 12 + nb * 2 + (w & 1)] = pv;
            sqb [(size_t)(gm0 + r) * 12 + nb * 2 + (w & 1)] = pq;
        }
    }
}

// ============================================================
// MFMA flash attention, S^T formulation, NO-MAX softmax, split-K=2.
// grid (28, NH, B*2), block 256. Writes unnormalized O (f16) + l.
// ============================================================
__global__ __launch_bounds__(256) void attn_mfma(
    const u16* __restrict__ big, const u16* __restrict__ vT,
    u16* __restrict__ op, float* __restrict__ lp)
{
    __shared__ __align__(16) u16 qs[64][72];        // bf16 [q][d pad 64]
    __shared__ __align__(16) u16 ks[2][64][72];     // bf16 [key][d pad 64]
    __shared__ __align__(16) u16 vts[2][48][68];    // f16  [d][key]

    const int tid  = threadIdx.x;
    const int lane = tid & 63, wave = tid >> 6;
    const int t = lane & 15, quad = lane >> 4;
    const int q0 = blockIdx.x * 64, h = blockIdx.y;
    const int b = blockIdx.z >> 1, sp = blockIdx.z & 1;
    const int tile0 = sp * 14;
    const u16* rowb = big + (size_t)b * BSTR * 1152;
    const u16* vTb  = vT + ((size_t)(b * 8 + h) * 48) * BSTR;

    {
        uint4 z = make_uint4(0, 0, 0, 0);
        for (int c = tid; c < 384; c += 256) {
            int reg = c >> 7, idx = c & 127;
            int rr = idx >> 1, hb = idx & 1;
            if (reg == 0) *(uint4*)&qs[rr][48 + hb * 8] = z;
            else          *(uint4*)&ks[reg - 1][rr][48 + hb * 8] = z;
        }
    }
    for (int c = tid; c < 384; c += 256) {
        int tok = c / 6, ch = c % 6;
        int n = q0 + tok;
        uint4 v = make_uint4(0, 0, 0, 0);
        if (n < NTOK)
            v = *(const uint4*)(rowb + (size_t)n * 1152 + h * 48 + ch * 8);
        *(uint4*)&qs[tok][ch * 8] = v;
    }

    const int c1v = tid + 256;
    const int ktok0 = tid / 6, kch0 = tid % 6;
    const int ktok1 = c1v / 6, kch1 = c1v % 6;
    const int vd0 = tid >> 3,  vch0 = tid & 7;
    const int vd1 = (c1v) >> 3, vch1 = c1v & 7;
    const bool two = (tid < 128);
    uint4 kr0, kr1, vr0, vr1;

#define PREFETCH(K0)                                                          \
    {                                                                         \
        int n0 = (K0) + ktok0;                                                \
        kr0 = (n0 < NTOK) ? *(const uint4*)(rowb + (size_t)n0 * 1152 + 384 +  \
                                            h * 48 + kch0 * 8)                \
                          : make_uint4(0, 0, 0, 0);                           \
        vr0 = *(const uint4*)(vTb + (size_t)vd0 * BSTR + (K0) + vch0 * 8);    \
        if (two) {                                                            \
            int n1 = (K0) + ktok1;                                            \
            kr1 = (n1 < NTOK) ? *(const uint4*)(rowb + (size_t)n1 * 1152 +    \
                                                384 + h * 48 + kch1 * 8)      \
                              : make_uint4(0, 0, 0, 0);                       \
            vr1 = *(const uint4*)(vTb + (size_t)vd1 * BSTR + (K0) + vch1 * 8);\
        }                                                                     \
    }
#define COMMIT(BUF)                                                           \
    {                                                                         \
        *(uint4*)&ks[BUF][ktok0][kch0 * 8] = kr0;                             \
        *(uint4*)&vts[BUF][vd0][vch0 * 8] = vr0;                              \
        if (two) {                                                            \
            *(uint4*)&ks[BUF][ktok1][kch1 * 8] = kr1;                         \
            *(uint4*)&vts[BUF][vd1][vch1 * 8] = vr1;                          \
        }                                                                     \
    }

    PREFETCH(tile0 * 64);
    COMMIT(0);
    __syncthreads();

    float l_lane = 0.f;
    floatx4 oacc[3];
#pragma unroll
    for (int dt = 0; dt < 3; ++dt) oacc[dt] = (floatx4){0.f, 0.f, 0.f, 0.f};

    for (int it = 0; it < 14; ++it) {
        const int k0 = (tile0 + it) * 64;
        const int cur = it & 1, nxt = cur ^ 1;
        if (it < 13) PREFETCH(k0 + 64);

        floatx4 sf[4];
#pragma unroll
        for (int f = 0; f < 4; ++f) sf[f] = (floatx4){0.f, 0.f, 0.f, 0.f};
        bf16x8 qb0 = ld8(&qs[wave * 16 + t][quad * 8]);
        bf16x8 qb1 = ld8(&qs[wave * 16 + t][32 + quad * 8]);
#pragma unroll
        for (int f = 0; f < 4; ++f) {
            bf16x8 ka0 = ld8(&ks[cur][f * 16 + t][quad * 8]);
            bf16x8 ka1 = ld8(&ks[cur][f * 16 + t][32 + quad * 8]);
            sf[f] = __builtin_amdgcn_mfma_f32_16x16x32_bf16(ka0, qb0, sf[f], 0, 0, 0);
            sf[f] = __builtin_amdgcn_mfma_f32_16x16x32_bf16(ka1, qb1, sf[f], 0, 0, 0);
        }
        if (k0 + 64 > NTOK) {
#pragma unroll
            for (int f = 0; f < 4; ++f)
#pragma unroll
                for (int r = 0; r < 4; ++r) {
                    bool valid = (k0 + f * 16 + quad * 4 + r) < NTOK;
                    if (!valid) sf[f][r] = -1e30f;
                }
        }
#pragma unroll
        for (int f = 0; f < 4; ++f)
#pragma unroll
            for (int r = 0; r < 4; ++r) {
                sf[f][r] = __expf(sf[f][r] * SCALE_);
                l_lane += sf[f][r];
            }

#pragma unroll
        for (int f = 0; f < 4; ++f) {
            halfx4 pa;
            pa[0] = (_Float16)sf[f][0]; pa[1] = (_Float16)sf[f][1];
            pa[2] = (_Float16)sf[f][2]; pa[3] = (_Float16)sf[f][3];
#pragma unroll
            for (int dt = 0; dt < 3; ++dt) {
                ushort4 vv = *(const ushort4*)&vts[cur][dt * 16 + t][f * 16 + quad * 4];
                halfx4 vb = __builtin_bit_cast(halfx4, vv);
                oacc[dt] = __builtin_amdgcn_mfma_f32_16x16x16f16(pa, vb, oacc[dt], 0, 0, 0);
            }
        }

        if (it < 13) COMMIT(nxt);
        __syncthreads();
    }
#undef PREFETCH
#undef COMMIT

    l_lane += __shfl_xor(l_lane, 16, 64);
    l_lane += __shfl_xor(l_lane, 32, 64);
    if (quad == 0)
        lp[((size_t)(sp * B_ + b) * BSTR + q0 + wave * 16 + t) * NH_ + h] = l_lane;

#pragma unroll
    for (int r = 0; r < 4; ++r) {
        int n = q0 + wave * 16 + quad * 4 + r;
        if (n >= BSTR) continue;
#pragma unroll
        for (int dt = 0; dt < 3; ++dt)
            op[((size_t)(sp * B_ + b) * BSTR + n) * EMB_ + h * 48 + dt * 16 + t] =
                f2h(oacc[dt][r]);
    }
}

// ============================================================
// Final LN (cls row) + head. grid B, block 384.
// ============================================================
__global__ __launch_bounds__(384) void head_kernel(
    const float* __restrict__ t, const float* __restrict__ nw,
    const float* __restrict__ nb, const float* __restrict__ hw,
    const float* __restrict__ hb, float* __restrict__ out)
{
    const int b = blockIdx.x;
    const int e = threadIdx.x;
    const int wave = e >> 6, lane = e & 63;
    __shared__ float red[6];
    __shared__ float nbuf[EMB_];

    float v = t[(size_t)b * BSTR * EMB_ + e];

    float s = v;
#pragma unroll
    for (int off = 32; off; off >>= 1) s += __shfl_xor(s, off, 64);
    if (lane == 0) red[wave] = s;
    __syncthreads();
    float tot = 0.f;
    for (int w2 = 0; w2 < 6; ++w2) tot += red[w2];
    const float mean = tot * (1.0f / EMB_);
    __syncthreads();

    float d = v - mean;
    float q = d * d;
#pragma unroll
    for (int off = 32; off; off >>= 1) q += __shfl_xor(q, off, 64);
    if (lane == 0) red[wave] = q;
    __syncthreads();
    float qt = 0.f;
    for (int w2 = 0; w2 < 6; ++w2) qt += red[w2];
    const float rstd = rsqrtf(qt * (1.0f / EMB_) + 1e-5f);
    nbuf[e] = d * rstd * nw[e] + nb[e];
    __syncthreads();

    for (int c = 0; c < NC_; ++c) {
        float p = nbuf[e] * hw[c * EMB_ + e];
#pragma unroll
        for (int off = 32; off; off >>= 1) p += __shfl_xor(p, off, 64);
        __syncthreads();
        if (lane == 0) red[wave] = p;
        __syncthreads();
        if (e == 0) {
            float sum = 0.f;
            for (int w2 = 0; w2 < 6; ++w2) sum += red[w2];
            out[b * NC_ + c] = sum + hb[c];
        }
    }
}

// ============================================================
extern "C" void kernel_launch(void* const* d_in, const int* in_sizes, int n_in,
                              void* d_out, int out_size, void* d_ws, size_t ws_size,
                              hipStream_t stream)
{
    const float* x         = (const float*)d_in[0];
    const float* conv_w    = (const float*)d_in[1];
    const float* conv_b    = (const float*)d_in[2];
    const float* cls_token = (const float*)d_in[3];
    const float* pos_embed = (const float*)d_in[4];
    const float* ln1_w     = (const float*)d_in[5];
    const float* ln1_b     = (const float*)d_in[6];
    const float* qkv_w     = (const float*)d_in[7];
    const float* qkv_b     = (const float*)d_in[8];
    const float* proj_w    = (const float*)d_in[9];
    const float* proj_b    = (const float*)d_in[10];
    const float* ln2_w     = (const float*)d_in[11];
    const float* ln2_b     = (const float*)d_in[12];
    const float* mlp_w1    = (const float*)d_in[13];
    const float* mlp_b1    = (const float*)d_in[14];
    const float* mlp_w2    = (const float*)d_in[15];
    const float* mlp_b2    = (const float*)d_in[16];
    const float* norm_w    = (const float*)d_in[17];
    const float* norm_b    = (const float*)d_in[18];
    const float* head_w    = (const float*)d_in[19];
    const float* head_b    = (const float*)d_in[20];
    float* out = (float*)d_out;

    // ---- workspace layout ----
    char* p = (char*)d_ws;
    float* t  = (float*)p;  p += (size_t)M_PAD * EMB_ * 4;   // fp32 residual
    u16* big  = (u16*)p;    p += (size_t)M_PAD * MLP_ * 2;   // bf16 qkv / mlp hidden
    u16* wqb  = (u16*)p;    p += (size_t)NL_ * 1152 * EMB_ * 2;
    u16* wpb  = (u16*)p;    p += (size_t)NL_ * EMB_ * EMB_ * 2;
    u16* w1b  = (u16*)p;    p += (size_t)NL_ * MLP_ * EMB_ * 2;
    u16* w2b  = (u16*)p;    p += (size_t)NL_ * EMB_ * MLP_ * 2;
    u16* cwb  = (u16*)p;    p += (size_t)CW_N * 2;           // bf16 conv_w
    u16* xb   = (u16*)p;    p += (size_t)B_ * 96 * 96 * 96 * 2;  // bf16 x
    u16* op   = (u16*)p;    p += 2 * OPSZ * 2;               // f16 partial O (2 splits)
    float* lp = (float*)p;  p += (size_t)2 * B_ * BSTR * NH_ * 4; // f32 partial l
    float* sumb = (float*)p; p += (size_t)M_PAD * 12 * 4;    // LN stats partials
    float* sqb  = (float*)p; p += (size_t)M_PAD * 12 * 4;
    // vT (f16) lives in big's unused tail (16 heads * 48 d * 1792 tok)
    u16* vT = big + (size_t)M_PAD * 1152;

    cvt_all<<<P5_ / 4 / 256, 256, 0, stream>>>(
        conv_w, x, qkv_w, proj_w, mlp_w1, mlp_w2,
        cwb, xb, wqb, wpb, w1b, w2b);

    patch_mfma<<<dim3(EMB_ / 64, 3456 / 64), 256, 0, stream>>>(
        xb, cwb, conv_b, cls_token, pos_embed, t, sumb, sqb);

    for (int l = 0; l < NL_; ++l) {
        // qkv = LN1(t) @ qkv_w^T + b : Q,K -> big, V -> vT (f16 transposed)
        gemm_ln<2, 2, 0, 1><<<dim3(1152 / 64, M_PAD / 64), 256, 0, stream>>>(
            t, sumb, sqb, ln1_w + l * EMB_, ln1_b + l * EMB_,
            wqb + (size_t)l * 1152 * EMB_, qkv_b + l * 1152, big, vT, 1152);
        attn_mfma<<<dim3(BSTR / 64, NH_, B_ * 2), 256, 0, stream>>>(big, vT, op, lp);
        // t += combine(op,lp) @ proj_w^T + b ; emit LN2 stats
        gemm_res<1><<<dim3(EMB_ / 64, M_PAD / 32), 256, 0, stream>>>(
            nullptr, op, lp, wpb + (size_t)l * EMB_ * EMB_, proj_b + l * EMB_,
            t, sumb, sqb, EMB_);
        // big = gelu(LN2(t) @ mlp_w1^T + b)
        gemm_ln<2, 2, 1, 0><<<dim3(MLP_ / 64, M_PAD / 64), 256, 0, stream>>>(
            t, sumb, sqb, ln2_w + l * EMB_, ln2_b + l * EMB_,
            w1b + (size_t)l * MLP_ * EMB_, mlp_b1 + l * MLP_, big, nullptr, MLP_);
        // t += big @ mlp_w2^T + b ; emit next-layer LN1 stats
        gemm_res<0><<<dim3(EMB_ / 64, M_PAD / 32), 256, 0, stream>>>(
            big, nullptr, nullptr, w2b + (size_t)l * EMB_ * MLP_, mlp_b2 + l * EMB_,
            t, sumb, sqb, MLP_);
    }

    head_kernel<<<B_, 384, 0, stream>>>(t, norm_w, norm_b, head_w, head_b, out);
}

// Round 9
// 659.864 us; speedup vs baseline: 1.2498x; 1.2498x over previous
//
#include <hip/hip_runtime.h>
#include <math.h>

// ---- problem constants ----
#define B_      2
#define EMB_    384
#define NH_     8
#define HD_     48
#define NTOK    1729       // NPATCH + 1
#define NPATCH_ 1728
#define MLP_    1536
#define NL_     6
#define NC_     2
#define BSTR    1792       // per-batch row stride (padded tokens)
#define M_PAD   3584       // 2 * BSTR
#define SCALE_  0.14433756729740643f   // 1/sqrt(48)
#define OPSZ    ((size_t)B_ * BSTR * EMB_)

typedef __bf16 bf16x8 __attribute__((ext_vector_type(8)));
typedef float floatx4 __attribute__((ext_vector_type(4)));
typedef _Float16 halfx4 __attribute__((ext_vector_type(4)));
typedef unsigned short u16;

__device__ __forceinline__ u16 f2b(float f) {
    unsigned int u = __float_as_uint(f);
    return (u16)((u + 0x7FFFu + ((u >> 16) & 1u)) >> 16);
}
__device__ __forceinline__ u16 f2h(float f) {
    _Float16 h = (_Float16)f;
    return __builtin_bit_cast(unsigned short, h);
}
__device__ __forceinline__ bf16x8 ld8(const u16* p) {       // 16B-aligned
    return *(const bf16x8*)p;
}

// ============================================================
// Merged fp32 -> bf16 convert: conv_w | x | qkv_w | proj_w | mlp_w1 | mlp_w2
// ============================================================
#define CW_N  196608      // 384*512
#define P0_   196608
#define P1_   1966080     // + x (1769472)
#define P2_   4620288     // + qkv_w (2654208)
#define P3_   5505024     // + proj_w (884736)
#define P4_   9043968     // + mlp_w1 (3538944)
#define P5_   12582912    // + mlp_w2 (3538944)
__global__ __launch_bounds__(256) void cvt_all(
    const float* __restrict__ cw, const float* __restrict__ x,
    const float* __restrict__ qw, const float* __restrict__ pw,
    const float* __restrict__ w1, const float* __restrict__ w2,
    u16* __restrict__ cwb, u16* __restrict__ xb, u16* __restrict__ qwb,
    u16* __restrict__ pwb, u16* __restrict__ w1b, u16* __restrict__ w2b)
{
    int i = (blockIdx.x * 256 + threadIdx.x) * 4;
    const float* s; u16* d; int off;
    if      (i < P0_) { s = cw; d = cwb; off = 0; }
    else if (i < P1_) { s = x;  d = xb;  off = P0_; }
    else if (i < P2_) { s = qw; d = qwb; off = P1_; }
    else if (i < P3_) { s = pw; d = pwb; off = P2_; }
    else if (i < P4_) { s = w1; d = w1b; off = P3_; }
    else              { s = w2; d = w2b; off = P4_; }
    i -= off;
    float4 v = *(const float4*)(s + i);
    ushort4 o;
    o.x = f2b(v.x); o.y = f2b(v.y); o.z = f2b(v.z); o.w = f2b(v.w);
    *(ushort4*)(d + i) = o;
}

// ============================================================
// Patch embed as bf16 MFMA GEMM. grid (6, 54), block 256.
// ============================================================
__global__ __launch_bounds__(256) void patch_mfma(
    const u16* __restrict__ xb, const u16* __restrict__ cwb,
    const float* __restrict__ cb, const float* __restrict__ cls,
    const float* __restrict__ pos, float* __restrict__ t)
{
    __shared__ __align__(16) u16 As[64][40];
    __shared__ __align__(16) u16 Bs[64][40];
    const int tid  = threadIdx.x;
    const int lane = tid & 63, w = tid >> 6;
    const int wm = (w >> 1) * 32, wn = (w & 1) * 32;
    const int m0g = blockIdx.y * 64, n0g = blockIdx.x * 64;
    const int cl = lane & 15, kh = (lane >> 4) * 8;

    if (blockIdx.x == 0 && blockIdx.y == 0) {
        for (int c = tid; c < 2 * EMB_; c += 256) {
            int bb = c / EMB_, e = c % EMB_;
            t[(size_t)bb * BSTR * EMB_ + e] = cls[e] + pos[e];
        }
    }

    const int sm = tid >> 2, skc = tid & 3;
    const int gm_s = m0g + sm;
    const int bb_s = gm_s / 1728, p_s = gm_s % 1728;
    const int pz = p_s / 144, py = (p_s / 12) % 12, px = p_s % 12;

    floatx4 acc[2][2];
#pragma unroll
    for (int i = 0; i < 2; ++i)
#pragma unroll
        for (int j = 0; j < 2; ++j) acc[i][j] = (floatx4){0.f, 0.f, 0.f, 0.f};

    for (int k0 = 0; k0 < 512; k0 += 32) {
        {
            int k = k0 + skc * 8;
            int dz = k >> 6, dy = (k >> 3) & 7;
            *(uint4*)&As[sm][skc * 8] =
                *(const uint4*)(xb + ((size_t)(bb_s * 96 + pz * 8 + dz) * 96 +
                                      py * 8 + dy) * 96 + px * 8);
            *(uint4*)&Bs[sm][skc * 8] =
                *(const uint4*)(cwb + (size_t)(n0g + sm) * 512 + k);
        }
        __syncthreads();
        bf16x8 af[2], bfr[2];
#pragma unroll
        for (int i = 0; i < 2; ++i) af[i] = ld8(&As[wm + 16 * i + cl][kh]);
#pragma unroll
        for (int j = 0; j < 2; ++j) bfr[j] = ld8(&Bs[wn + 16 * j + cl][kh]);
#pragma unroll
        for (int i = 0; i < 2; ++i)
#pragma unroll
            for (int j = 0; j < 2; ++j)
                acc[i][j] = __builtin_amdgcn_mfma_f32_16x16x32_bf16(
                    af[i], bfr[j], acc[i][j], 0, 0, 0);
        __syncthreads();
    }

    const int r0 = (lane >> 4) * 4;
#pragma unroll
    for (int j = 0; j < 2; ++j) {
        int gn = n0g + wn + 16 * j + cl;
        float bn = cb[gn];
#pragma unroll
        for (int i = 0; i < 2; ++i) {
#pragma unroll
            for (int r = 0; r < 4; ++r) {
                int gm = m0g + wm + 16 * i + r0 + r;
                int bb = gm / 1728, p = gm % 1728;
                t[((size_t)bb * BSTR + 1 + p) * EMB_ + gn] =
                    acc[i][j][r] + bn + pos[(size_t)(1 + p) * EMB_ + gn];
            }
        }
    }
}

// ============================================================
// LayerNorm: one wave per 384-elem row; emits bf16.
// ============================================================
__global__ __launch_bounds__(256) void ln_kernel(
    const float* __restrict__ x, const float* __restrict__ w,
    const float* __restrict__ b, u16* __restrict__ y)
{
    const int wave = threadIdx.x >> 6;
    const int lane = threadIdx.x & 63;
    const int tok  = blockIdx.x * 4 + wave;
    if (tok >= NTOK) return;
    const size_t row = (size_t)blockIdx.y * BSTR + tok;
    const float* xr = x + row * EMB_;

    float v[6];
    float s = 0.f;
#pragma unroll
    for (int j = 0; j < 6; ++j) { v[j] = xr[lane + 64 * j]; s += v[j]; }
#pragma unroll
    for (int off = 32; off; off >>= 1) s += __shfl_xor(s, off, 64);
    const float mean = s * (1.0f / EMB_);

    float q = 0.f;
#pragma unroll
    for (int j = 0; j < 6; ++j) { float d = v[j] - mean; q += d * d; }
#pragma unroll
    for (int off = 32; off; off >>= 1) q += __shfl_xor(q, off, 64);
    const float rstd = rsqrtf(q * (1.0f / EMB_) + 1e-5f);

    u16* yr = y + row * EMB_;
#pragma unroll
    for (int j = 0; j < 6; ++j) {
        int e = lane + 64 * j;
        yr[e] = f2b((v[j] - mean) * rstd * w[e] + b[e]);
    }
}

// ============================================================
// bf16 MFMA GEMM v2: BK=64 (half the barriers), LDS stride 72.
// Tile TM=32*FI x TN=32*FJ, 256 threads (2x2 waves).
// RES=1: T (fp32, stride EMB_) += A@W^T + bias  (residual update)
// else : Cb (bf16) = act(A@W^T + bias); VT=1 routes cols [768,1152)
//        transposed (f16) into vt for attention V.
// ============================================================
template<int FI, int FJ, int ACT, int VT, int RES>
__global__ __launch_bounds__(256) void gemm2(
    const u16* __restrict__ A, const u16* __restrict__ W,
    const float* __restrict__ bias, float* __restrict__ T,
    u16* __restrict__ Cb, u16* __restrict__ vt, int N, int K)
{
    constexpr int TM = 32 * FI;
    constexpr int TN = 32 * FJ;
    __shared__ __align__(16) u16 As[TM][72];
    __shared__ __align__(16) u16 Bs[TN][72];
    const int tid  = threadIdx.x;
    const int lane = tid & 63, w = tid >> 6;
    const int wm = (w >> 1) * (16 * FI);
    const int wn = (w & 1) * (16 * FJ);
    const int m0g = blockIdx.y * TM, n0g = blockIdx.x * TN;
    const int cl = lane & 15, kh = (lane >> 4) * 8;

    floatx4 acc[FI][FJ];
#pragma unroll
    for (int i = 0; i < FI; ++i)
#pragma unroll
        for (int j = 0; j < FJ; ++j)
            acc[i][j] = (floatx4){0.f, 0.f, 0.f, 0.f};

    for (int k0 = 0; k0 < K; k0 += 64) {
#pragma unroll
        for (int u = 0; u < TM / 32; ++u) {
            int c = tid + u * 256;
            int m = c >> 3, kc = c & 7;
            *(uint4*)&As[m][kc * 8] =
                *(const uint4*)(A + (size_t)(m0g + m) * K + k0 + kc * 8);
        }
#pragma unroll
        for (int u = 0; u < TN / 32; ++u) {
            int c = tid + u * 256;
            int n = c >> 3, kc = c & 7;
            *(uint4*)&Bs[n][kc * 8] =
                *(const uint4*)(W + (size_t)(n0g + n) * K + k0 + kc * 8);
        }
        __syncthreads();

        bf16x8 af[FI][2], bfr[FJ][2];
#pragma unroll
        for (int i = 0; i < FI; ++i) {
            af[i][0] = ld8(&As[wm + 16 * i + cl][kh]);
            af[i][1] = ld8(&As[wm + 16 * i + cl][32 + kh]);
        }
#pragma unroll
        for (int j = 0; j < FJ; ++j) {
            bfr[j][0] = ld8(&Bs[wn + 16 * j + cl][kh]);
            bfr[j][1] = ld8(&Bs[wn + 16 * j + cl][32 + kh]);
        }
#pragma unroll
        for (int i = 0; i < FI; ++i)
#pragma unroll
            for (int j = 0; j < FJ; ++j) {
                acc[i][j] = __builtin_amdgcn_mfma_f32_16x16x32_bf16(
                    af[i][0], bfr[j][0], acc[i][j], 0, 0, 0);
                acc[i][j] = __builtin_amdgcn_mfma_f32_16x16x32_bf16(
                    af[i][1], bfr[j][1], acc[i][j], 0, 0, 0);
            }
        __syncthreads();
    }

    const int r0 = (lane >> 4) * 4;
#pragma unroll
    for (int j = 0; j < FJ; ++j) {
        int gn = n0g + wn + 16 * j + cl;
        float bn = bias[gn];
#pragma unroll
        for (int i = 0; i < FI; ++i) {
            int gm0 = m0g + wm + 16 * i + r0;
            if (RES) {
#pragma unroll
                for (int r = 0; r < 4; ++r) {
                    size_t idx = (size_t)(gm0 + r) * EMB_ + gn;
                    T[idx] += acc[i][j][r] + bn;
                }
            } else {
                float v[4];
#pragma unroll
                for (int r = 0; r < 4; ++r) {
                    float vv = acc[i][j][r] + bn;
                    if (ACT) vv = 0.5f * vv * (1.0f + erff(vv * 0.70710678118654752f));
                    v[r] = vv;
                }
                if (VT && gn >= 768) {
                    int hh = (gn - 768) / 48, dd = (gn - 768) % 48;
                    int bb = gm0 / BSTR, tok = gm0 - bb * BSTR;
                    ushort4 o;
                    o.x = f2h(v[0]); o.y = f2h(v[1]);
                    o.z = f2h(v[2]); o.w = f2h(v[3]);
                    *(ushort4*)(vt + ((size_t)(bb * 8 + hh) * 48 + dd) * BSTR + tok) = o;
                } else {
#pragma unroll
                    for (int r = 0; r < 4; ++r)
                        Cb[(size_t)(gm0 + r) * N + gn] = f2b(v[r]);
                }
            }
        }
    }
}

// ============================================================
// MFMA flash attention, S^T formulation, NO-MAX softmax, split-K=2.
// grid (28, NH, B*2), block 256. Writes unnormalized O (f16) + l.
// ============================================================
__global__ __launch_bounds__(256) void attn_mfma(
    const u16* __restrict__ big, const u16* __restrict__ vT,
    u16* __restrict__ op, float* __restrict__ lp)
{
    __shared__ __align__(16) u16 qs[64][72];        // bf16 [q][d pad 64]
    __shared__ __align__(16) u16 ks[2][64][72];     // bf16 [key][d pad 64]
    __shared__ __align__(16) u16 vts[2][48][68];    // f16  [d][key]

    const int tid  = threadIdx.x;
    const int lane = tid & 63, wave = tid >> 6;
    const int t = lane & 15, quad = lane >> 4;
    const int q0 = blockIdx.x * 64, h = blockIdx.y;
    const int b = blockIdx.z >> 1, sp = blockIdx.z & 1;
    const int tile0 = sp * 14;
    const u16* rowb = big + (size_t)b * BSTR * 1152;
    const u16* vTb  = vT + ((size_t)(b * 8 + h) * 48) * BSTR;

    {
        uint4 z = make_uint4(0, 0, 0, 0);
        for (int c = tid; c < 384; c += 256) {
            int reg = c >> 7, idx = c & 127;
            int rr = idx >> 1, hb = idx & 1;
            if (reg == 0) *(uint4*)&qs[rr][48 + hb * 8] = z;
            else          *(uint4*)&ks[reg - 1][rr][48 + hb * 8] = z;
        }
    }
    for (int c = tid; c < 384; c += 256) {
        int tok = c / 6, ch = c % 6;
        int n = q0 + tok;
        uint4 v = make_uint4(0, 0, 0, 0);
        if (n < NTOK)
            v = *(const uint4*)(rowb + (size_t)n * 1152 + h * 48 + ch * 8);
        *(uint4*)&qs[tok][ch * 8] = v;
    }

    const int c1v = tid + 256;
    const int ktok0 = tid / 6, kch0 = tid % 6;
    const int ktok1 = c1v / 6, kch1 = c1v % 6;
    const int vd0 = tid >> 3,  vch0 = tid & 7;
    const int vd1 = (c1v) >> 3, vch1 = c1v & 7;
    const bool two = (tid < 128);
    uint4 kr0, kr1, vr0, vr1;

#define PREFETCH(K0)                                                          \
    {                                                                         \
        int n0 = (K0) + ktok0;                                                \
        kr0 = (n0 < NTOK) ? *(const uint4*)(rowb + (size_t)n0 * 1152 + 384 +  \
                                            h * 48 + kch0 * 8)                \
                          : make_uint4(0, 0, 0, 0);                           \
        vr0 = *(const uint4*)(vTb + (size_t)vd0 * BSTR + (K0) + vch0 * 8);    \
        if (two) {                                                            \
            int n1 = (K0) + ktok1;                                            \
            kr1 = (n1 < NTOK) ? *(const uint4*)(rowb + (size_t)n1 * 1152 +    \
                                                384 + h * 48 + kch1 * 8)      \
                              : make_uint4(0, 0, 0, 0);                       \
            vr1 = *(const uint4*)(vTb + (size_t)vd1 * BSTR + (K0) + vch1 * 8);\
        }                                                                     \
    }
#define COMMIT(BUF)                                                           \
    {                                                                         \
        *(uint4*)&ks[BUF][ktok0][kch0 * 8] = kr0;                             \
        *(uint4*)&vts[BUF][vd0][vch0 * 8] = vr0;                              \
        if (two) {                                                            \
            *(uint4*)&ks[BUF][ktok1][kch1 * 8] = kr1;                         \
            *(uint4*)&vts[BUF][vd1][vch1 * 8] = vr1;                          \
        }                                                                     \
    }

    PREFETCH(tile0 * 64);
    COMMIT(0);
    __syncthreads();

    float l_lane = 0.f;
    floatx4 oacc[3];
#pragma unroll
    for (int dt = 0; dt < 3; ++dt) oacc[dt] = (floatx4){0.f, 0.f, 0.f, 0.f};

    for (int it = 0; it < 14; ++it) {
        const int k0 = (tile0 + it) * 64;
        const int cur = it & 1, nxt = cur ^ 1;
        if (it < 13) PREFETCH(k0 + 64);

        floatx4 sf[4];
#pragma unroll
        for (int f = 0; f < 4; ++f) sf[f] = (floatx4){0.f, 0.f, 0.f, 0.f};
        bf16x8 qb0 = ld8(&qs[wave * 16 + t][quad * 8]);
        bf16x8 qb1 = ld8(&qs[wave * 16 + t][32 + quad * 8]);
#pragma unroll
        for (int f = 0; f < 4; ++f) {
            bf16x8 ka0 = ld8(&ks[cur][f * 16 + t][quad * 8]);
            bf16x8 ka1 = ld8(&ks[cur][f * 16 + t][32 + quad * 8]);
            sf[f] = __builtin_amdgcn_mfma_f32_16x16x32_bf16(ka0, qb0, sf[f], 0, 0, 0);
            sf[f] = __builtin_amdgcn_mfma_f32_16x16x32_bf16(ka1, qb1, sf[f], 0, 0, 0);
        }
        if (k0 + 64 > NTOK) {
#pragma unroll
            for (int f = 0; f < 4; ++f)
#pragma unroll
                for (int r = 0; r < 4; ++r) {
                    bool valid = (k0 + f * 16 + quad * 4 + r) < NTOK;
                    if (!valid) sf[f][r] = -1e30f;
                }
        }
#pragma unroll
        for (int f = 0; f < 4; ++f)
#pragma unroll
            for (int r = 0; r < 4; ++r) {
                sf[f][r] = __expf(sf[f][r] * SCALE_);
                l_lane += sf[f][r];
            }

#pragma unroll
        for (int f = 0; f < 4; ++f) {
            halfx4 pa;
            pa[0] = (_Float16)sf[f][0]; pa[1] = (_Float16)sf[f][1];
            pa[2] = (_Float16)sf[f][2]; pa[3] = (_Float16)sf[f][3];
#pragma unroll
            for (int dt = 0; dt < 3; ++dt) {
                ushort4 vv = *(const ushort4*)&vts[cur][dt * 16 + t][f * 16 + quad * 4];
                halfx4 vb = __builtin_bit_cast(halfx4, vv);
                oacc[dt] = __builtin_amdgcn_mfma_f32_16x16x16f16(pa, vb, oacc[dt], 0, 0, 0);
            }
        }

        if (it < 13) COMMIT(nxt);
        __syncthreads();
    }
#undef PREFETCH
#undef COMMIT

    l_lane += __shfl_xor(l_lane, 16, 64);
    l_lane += __shfl_xor(l_lane, 32, 64);
    if (quad == 0)
        lp[((size_t)(sp * B_ + b) * BSTR + q0 + wave * 16 + t) * NH_ + h] = l_lane;

#pragma unroll
    for (int r = 0; r < 4; ++r) {
        int n = q0 + wave * 16 + quad * 4 + r;
        if (n >= NTOK) continue;
#pragma unroll
        for (int dt = 0; dt < 3; ++dt)
            op[((size_t)(sp * B_ + b) * BSTR + n) * EMB_ + h * 48 + dt * 16 + t] =
                f2h(oacc[dt][r]);
    }
}

// ============================================================
// Combine splits: ao = bf16((O0 + O1) / (l0 + l1)). grid 1344, block 256.
// ============================================================
__global__ __launch_bounds__(256) void attn_combine(
    const u16* __restrict__ op, const float* __restrict__ lp,
    u16* __restrict__ ao)
{
    int g = blockIdx.x * 256 + threadIdx.x;   // group of 4 elems
    int e4 = g % 96;
    int rem = g / 96;
    int n = rem % BSTR;
    int b = rem / BSTR;
    int e = e4 * 4;
    size_t base = ((size_t)b * BSTR + n) * EMB_ + e;
    if (n >= NTOK) {
        *(ushort4*)(ao + base) = make_ushort4(0, 0, 0, 0);
        return;
    }
    int h = e / 48;
    ushort4 a4 = *(const ushort4*)(op + base);
    ushort4 b4 = *(const ushort4*)(op + OPSZ + base);
    halfx4 ha = __builtin_bit_cast(halfx4, a4);
    halfx4 hb = __builtin_bit_cast(halfx4, b4);
    float l0 = lp[((size_t)b * BSTR + n) * NH_ + h];
    float l1 = lp[((size_t)(B_ + b) * BSTR + n) * NH_ + h];
    float rinv = 1.0f / (l0 + l1);
    ushort4 o;
    o.x = f2b(((float)ha[0] + (float)hb[0]) * rinv);
    o.y = f2b(((float)ha[1] + (float)hb[1]) * rinv);
    o.z = f2b(((float)ha[2] + (float)hb[2]) * rinv);
    o.w = f2b(((float)ha[3] + (float)hb[3]) * rinv);
    *(ushort4*)(ao + base) = o;
}

// ============================================================
// Final LN (cls row) + head. grid B, block 384.
// ============================================================
__global__ __launch_bounds__(384) void head_kernel(
    const float* __restrict__ t, const float* __restrict__ nw,
    const float* __restrict__ nb, const float* __restrict__ hw,
    const float* __restrict__ hb, float* __restrict__ out)
{
    const int b = blockIdx.x;
    const int e = threadIdx.x;
    const int wave = e >> 6, lane = e & 63;
    __shared__ float red[6];
    __shared__ float nbuf[EMB_];

    float v = t[(size_t)b * BSTR * EMB_ + e];

    float s = v;
#pragma unroll
    for (int off = 32; off; off >>= 1) s += __shfl_xor(s, off, 64);
    if (lane == 0) red[wave] = s;
    __syncthreads();
    float tot = 0.f;
    for (int w2 = 0; w2 < 6; ++w2) tot += red[w2];
    const float mean = tot * (1.0f / EMB_);
    __syncthreads();

    float d = v - mean;
    float q = d * d;
#pragma unroll
    for (int off = 32; off; off >>= 1) q += __shfl_xor(q, off, 64);
    if (lane == 0) red[wave] = q;
    __syncthreads();
    float qt = 0.f;
    for (int w2 = 0; w2 < 6; ++w2) qt += red[w2];
    const float rstd = rsqrtf(qt * (1.0f / EMB_) + 1e-5f);
    nbuf[e] = d * rstd * nw[e] + nb[e];
    __syncthreads();

    for (int c = 0; c < NC_; ++c) {
        float p = nbuf[e] * hw[c * EMB_ + e];
#pragma unroll
        for (int off = 32; off; off >>= 1) p += __shfl_xor(p, off, 64);
        __syncthreads();
        if (lane == 0) red[wave] = p;
        __syncthreads();
        if (e == 0) {
            float sum = 0.f;
            for (int w2 = 0; w2 < 6; ++w2) sum += red[w2];
            out[b * NC_ + c] = sum + hb[c];
        }
    }
}

// ============================================================
extern "C" void kernel_launch(void* const* d_in, const int* in_sizes, int n_in,
                              void* d_out, int out_size, void* d_ws, size_t ws_size,
                              hipStream_t stream)
{
    const float* x         = (const float*)d_in[0];
    const float* conv_w    = (const float*)d_in[1];
    const float* conv_b    = (const float*)d_in[2];
    const float* cls_token = (const float*)d_in[3];
    const float* pos_embed = (const float*)d_in[4];
    const float* ln1_w     = (const float*)d_in[5];
    const float* ln1_b     = (const float*)d_in[6];
    const float* qkv_w     = (const float*)d_in[7];
    const float* qkv_b     = (const float*)d_in[8];
    const float* proj_w    = (const float*)d_in[9];
    const float* proj_b    = (const float*)d_in[10];
    const float* ln2_w     = (const float*)d_in[11];
    const float* ln2_b     = (const float*)d_in[12];
    const float* mlp_w1    = (const float*)d_in[13];
    const float* mlp_b1    = (const float*)d_in[14];
    const float* mlp_w2    = (const float*)d_in[15];
    const float* mlp_b2    = (const float*)d_in[16];
    const float* norm_w    = (const float*)d_in[17];
    const float* norm_b    = (const float*)d_in[18];
    const float* head_w    = (const float*)d_in[19];
    const float* head_b    = (const float*)d_in[20];
    float* out = (float*)d_out;

    // ---- workspace layout ----
    char* p = (char*)d_ws;
    float* t  = (float*)p;  p += (size_t)M_PAD * EMB_ * 4;   // fp32 residual
    u16* h    = (u16*)p;    p += (size_t)M_PAD * EMB_ * 2;   // bf16 LN out
    u16* big  = (u16*)p;    p += (size_t)M_PAD * MLP_ * 2;   // bf16 qkv / mlp hidden
    u16* ao   = (u16*)p;    p += (size_t)M_PAD * EMB_ * 2;   // bf16 attn out
    u16* wqb  = (u16*)p;    p += (size_t)NL_ * 1152 * EMB_ * 2;
    u16* wpb  = (u16*)p;    p += (size_t)NL_ * EMB_ * EMB_ * 2;
    u16* w1b  = (u16*)p;    p += (size_t)NL_ * MLP_ * EMB_ * 2;
    u16* w2b  = (u16*)p;    p += (size_t)NL_ * EMB_ * MLP_ * 2;
    u16* cwb  = (u16*)p;    p += (size_t)CW_N * 2;           // bf16 conv_w
    u16* xb   = (u16*)p;    p += (size_t)B_ * 96 * 96 * 96 * 2;  // bf16 x
    u16* op   = (u16*)p;    p += 2 * OPSZ * 2;               // f16 partial O (2 splits)
    float* lp = (float*)p;  p += (size_t)2 * B_ * BSTR * NH_ * 4; // f32 partial l
    // vT (f16) lives in big's unused tail (16 heads * 48 d * 1792 tok)
    u16* vT = big + (size_t)M_PAD * 1152;

    cvt_all<<<P5_ / 4 / 256, 256, 0, stream>>>(
        conv_w, x, qkv_w, proj_w, mlp_w1, mlp_w2,
        cwb, xb, wqb, wpb, w1b, w2b);

    patch_mfma<<<dim3(EMB_ / 64, 3456 / 64), 256, 0, stream>>>(
        xb, cwb, conv_b, cls_token, pos_embed, t);

    const dim3 ln_grid((NTOK + 3) / 4, B_);
    for (int l = 0; l < NL_; ++l) {
        ln_kernel<<<ln_grid, 256, 0, stream>>>(t, ln1_w + l * EMB_, ln1_b + l * EMB_, h);
        // qkv: Q,K -> big (bf16); V -> vT (f16 transposed). 64x128 tiles, BK=64.
        gemm2<2, 4, 0, 1, 0><<<dim3(1152 / 128, M_PAD / 64), 256, 0, stream>>>(
            h, wqb + (size_t)l * 1152 * EMB_, qkv_b + l * 1152,
            nullptr, big, vT, 1152, EMB_);
        attn_mfma<<<dim3(BSTR / 64, NH_, B_ * 2), 256, 0, stream>>>(big, vT, op, lp);
        attn_combine<<<(int)(OPSZ / 4 / 256), 256, 0, stream>>>(op, lp, ao);
        // t += ao @ proj_w^T + b. 32x64 tiles, BK=64.
        gemm2<1, 2, 0, 0, 1><<<dim3(EMB_ / 64, M_PAD / 32), 256, 0, stream>>>(
            ao, wpb + (size_t)l * EMB_ * EMB_, proj_b + l * EMB_,
            t, nullptr, nullptr, EMB_, EMB_);
        ln_kernel<<<ln_grid, 256, 0, stream>>>(t, ln2_w + l * EMB_, ln2_b + l * EMB_, h);
        // big = gelu(h @ mlp_w1^T + b). 64x128 tiles, BK=64.
        gemm2<2, 4, 1, 0, 0><<<dim3(MLP_ / 128, M_PAD / 64), 256, 0, stream>>>(
            h, w1b + (size_t)l * MLP_ * EMB_, mlp_b1 + l * MLP_,
            nullptr, big, nullptr, MLP_, EMB_);
        // t += big @ mlp_w2^T + b. 32x64 tiles, BK=64, K=1536.
        gemm2<1, 2, 0, 0, 1><<<dim3(EMB_ / 64, M_PAD / 32), 256, 0, stream>>>(
            big, w2b + (size_t)l * EMB_ * MLP_, mlp_b2 + l * EMB_,
            t, nullptr, nullptr, EMB_, MLP_);
    }

    head_kernel<<<B_, 384, 0, stream>>>(t, norm_w, norm_b, head_w, head_b, out);
}